// Round 6
// baseline (106.696 us; speedup 1.0000x reference)
//
#include <hip/hip_runtime.h>

#define NGRID 1024
#define EPS_DX 1e-10f

typedef float f32x4 __attribute__((ext_vector_type(4)));
typedef float f32x2 __attribute__((ext_vector_type(2)));

// ---------------------------------------------------------------------------
// Kernel A: build the two adaptive grids (1024 floats each) into d_ws.
// ---------------------------------------------------------------------------
__global__ __launch_bounds__(1024) void build_grids(
    const float* __restrict__ incr_x,
    const float* __restrict__ incr_y,
    float* __restrict__ gx,
    float* __restrict__ gy)
{
    const float* incr = (blockIdx.x == 0) ? incr_x : incr_y;
    float* g = (blockIdx.x == 0) ? gx : gy;

    const int m = NGRID - 1;   // 1023 increments
    __shared__ double s[NGRID];

    int t = threadIdx.x;
    double v = 0.0;
    if (t < m) {
        double x = (double)incr[t];
        double sp = log1p(exp(x));          // softplus
        v = fmax(sp, 1e-6);
    }
    s[t] = v;
    __syncthreads();

    #pragma unroll
    for (int off = 1; off < NGRID; off <<= 1) {
        double add = (t >= off) ? s[t - off] : 0.0;
        __syncthreads();
        s[t] += add;
        __syncthreads();
    }

    double total = s[m - 1];
    if (t < m - 1) g[t + 1] = (float)(s[t] / total);
    if (t == 0) {
        g[0] = 0.0f;
        g[NGRID - 1] = 1.0f;
    }
}

// ---------------------------------------------------------------------------
// Kernel A2: pack horizontal pairs (u[i][j], u[i][j+1]) as 2xbf16 in 4 bytes.
// Table is 1024x1024x4B = 4 MB -> L2-resident. RNE rounding.
// ---------------------------------------------------------------------------
__device__ __forceinline__ unsigned int bf16_rne(float x)
{
    unsigned int v = __float_as_uint(x);
    return (v + 0x7FFFu + ((v >> 16) & 1u)) >> 16;
}

__global__ __launch_bounds__(256) void build_pairs(
    const float* __restrict__ u, unsigned int* __restrict__ UH)
{
    int t = blockIdx.x * 256 + threadIdx.x;
    if (t >= NGRID * NGRID) return;
    int j = t & (NGRID - 1);
    float a = u[t];
    float b = (j < NGRID - 1) ? u[t + 1] : 0.0f;   // j=1023 never read
    UH[t] = bf16_rne(a) | (bf16_rne(b) << 16);
}

// ---------------------------------------------------------------------------
// Single-LDS-access cell lookup. Q[j] = (g[j-1], g[j], g[j+1], g[j+2]).
// Predict j = floor(x*1023); fix up by at most one step using only Q[j].
// Reproduces clip(searchsorted(g,x,'left')-1, 0, 1022) exactly (semantics
// identical to the find_cell validated in R1-R5; d=+1 at j=1022 impossible
// since g[1023]=1 > x, d=-1 blocked at j=0).
// ---------------------------------------------------------------------------
__device__ __forceinline__ void find_cell6(float x, const f32x4* __restrict__ Q,
                                           int& jout, float& gl, float& gr)
{
    int j = (int)(x * 1023.0f);
    j = min(max(j, 0), NGRID - 2);
    f32x4 v = Q[j];
    bool adv = (v.z < x);                       // g[j+1] < x  -> step right
    bool ret = (!adv) && (j > 0) && (v.y >= x); // g[j]  >= x  -> step left
    gl = adv ? v.z : (ret ? v.x : v.y);
    gr = adv ? v.w : (ret ? v.y : v.z);
    jout = j + (adv ? 1 : (ret ? -1 : 0));
}

// ---------------------------------------------------------------------------
// Kernel B: grid-stride, 2 points per iteration, unroll 2.
// Per iteration: 1 coalesced f32x4 load, 4 ds_read_b128, 4 dword gathers
// (L2-resident bf16-pair table), 1 coalesced f32x2 NT store.
// ---------------------------------------------------------------------------
__global__ __launch_bounds__(512) void interp_kernel6(
    const f32x4* __restrict__ xy,
    const unsigned int* __restrict__ UH,
    const float* __restrict__ gx,
    const float* __restrict__ gy,
    f32x2* __restrict__ out2,
    int nq)                          // number of xy float4s (= N_EVAL/2)
{
    __shared__ f32x4 QX[NGRID];
    __shared__ f32x4 QY[NGRID];
    for (int i = threadIdx.x; i < NGRID; i += blockDim.x) {
        float a = (i > 0) ? gx[i - 1] : 0.0f;
        float b = gx[i];
        float c = (i < NGRID - 1) ? gx[i + 1] : 2.0f;  // pads never consumed
        float d = (i < NGRID - 2) ? gx[i + 2] : 2.0f;
        QX[i] = (f32x4){a, b, c, d};
        a = (i > 0) ? gy[i - 1] : 0.0f;
        b = gy[i];
        c = (i < NGRID - 1) ? gy[i + 1] : 2.0f;
        d = (i < NGRID - 2) ? gy[i + 2] : 2.0f;
        QY[i] = (f32x4){a, b, c, d};
    }
    __syncthreads();

    int tid = blockIdx.x * blockDim.x + threadIdx.x;
    int nthreads = gridDim.x * blockDim.x;

    #pragma unroll 2
    for (int q = tid; q < nq; q += nthreads) {
        f32x4 p = __builtin_nontemporal_load(&xy[q]);

        int jxa, jya, jxb, jyb;
        float xla, xra, yla, yra, xlb, xrb, ylb, yrb;
        find_cell6(p.x, QX, jxa, xla, xra);
        find_cell6(p.y, QY, jya, yla, yra);
        find_cell6(p.z, QX, jxb, xlb, xrb);
        find_cell6(p.w, QY, jyb, ylb, yrb);

        int ia = (jxa << 10) + jya;
        int ib = (jxb << 10) + jyb;

        // 4 independent gathers, all issued before use
        unsigned int va = UH[ia];            // (u00,u01) point a
        unsigned int wa = UH[ia + NGRID];    // (u10,u11) point a
        unsigned int vb = UH[ib];
        unsigned int wb = UH[ib + NGRID];

        f32x2 r;
        {
            float ax = (xra - p.x) * __builtin_amdgcn_rcpf(fmaxf(xra - xla, EPS_DX));
            float ay = (yra - p.y) * __builtin_amdgcn_rcpf(fmaxf(yra - yla, EPS_DX));
            float bx = 1.0f - ax, by = 1.0f - ay;
            float u00 = __uint_as_float(va << 16);
            float u01 = __uint_as_float(va & 0xFFFF0000u);
            float u10 = __uint_as_float(wa << 16);
            float u11 = __uint_as_float(wa & 0xFFFF0000u);
            r.x = ax * (ay * u00 + by * u01) + bx * (ay * u10 + by * u11);
        }
        {
            float ax = (xrb - p.z) * __builtin_amdgcn_rcpf(fmaxf(xrb - xlb, EPS_DX));
            float ay = (yrb - p.w) * __builtin_amdgcn_rcpf(fmaxf(yrb - ylb, EPS_DX));
            float bx = 1.0f - ax, by = 1.0f - ay;
            float u00 = __uint_as_float(vb << 16);
            float u01 = __uint_as_float(vb & 0xFFFF0000u);
            float u10 = __uint_as_float(wb << 16);
            float u11 = __uint_as_float(wb & 0xFFFF0000u);
            r.y = ax * (ay * u00 + by * u01) + bx * (ay * u10 + by * u11);
        }
        __builtin_nontemporal_store(r, &out2[q]);
    }
}

// ---------------------------------------------------------------------------
// Fallback (ws too small): R2-style 4-pt kernel gathering u directly.
// ---------------------------------------------------------------------------
__device__ __forceinline__ int find_cell(float x, const float2* __restrict__ PG,
                                         float& gl, float& gr)
{
    int j = (int)(x * 1023.0f);
    j = min(max(j, 0), NGRID - 2);
    float2 p = PG[j];
    int d = (p.y < x) ? 1 : ((j > 0 && p.x >= x) ? -1 : 0);
    j += d;
    float2 q = PG[j];
    gl = q.x; gr = q.y;
    return j;
}

__global__ __launch_bounds__(512) void interp_kernel4(
    const f32x4* __restrict__ xy,
    const float* __restrict__ u,
    const float* __restrict__ gx,
    const float* __restrict__ gy,
    f32x4* __restrict__ out,
    int nf)
{
    __shared__ float2 PGX[NGRID];
    __shared__ float2 PGY[NGRID];
    for (int i = threadIdx.x; i < NGRID - 1; i += blockDim.x) {
        PGX[i] = make_float2(gx[i], gx[i + 1]);
        PGY[i] = make_float2(gy[i], gy[i + 1]);
    }
    __syncthreads();

    int f = blockIdx.x * blockDim.x + threadIdx.x;
    if (f >= nf) return;

    f32x4 a = __builtin_nontemporal_load(&xy[2 * f]);
    f32x4 b = __builtin_nontemporal_load(&xy[2 * f + 1]);
    float xs[4] = {a.x, a.z, b.x, b.z};
    float ys[4] = {a.y, a.w, b.y, b.w};

    int jx[4], jy[4];
    float xl[4], xr[4], yl[4], yr[4];
    #pragma unroll
    for (int k = 0; k < 4; ++k) {
        jx[k] = find_cell(xs[k], PGX, xl[k], xr[k]);
        jy[k] = find_cell(ys[k], PGY, yl[k], yr[k]);
    }
    float u00[4], u10[4], u01[4], u11[4];
    #pragma unroll
    for (int k = 0; k < 4; ++k) {
        const float* up = u + jx[k] * NGRID + jy[k];
        u00[k] = up[0];
        u01[k] = up[1];
        u10[k] = up[NGRID];
        u11[k] = up[NGRID + 1];
    }
    f32x4 r;
    #pragma unroll
    for (int k = 0; k < 4; ++k) {
        float dx = fmaxf(xr[k] - xl[k], EPS_DX);
        float dy = fmaxf(yr[k] - yl[k], EPS_DX);
        float n1xv = (xr[k] - xs[k]) / dx;
        float n2xv = (xs[k] - xl[k]) / dx;
        float n1yv = (yr[k] - ys[k]) / dy;
        float n2yv = (ys[k] - yl[k]) / dy;
        r[k] = n1xv * n1yv * u00[k] + n2xv * n1yv * u10[k]
             + n1xv * n2yv * u01[k] + n2xv * n2yv * u11[k];
    }
    __builtin_nontemporal_store(r, &out[f]);
}

// ---------------------------------------------------------------------------
extern "C" void kernel_launch(void* const* d_in, const int* in_sizes, int n_in,
                              void* d_out, int out_size, void* d_ws, size_t ws_size,
                              hipStream_t stream)
{
    const float* x_eval = (const float*)d_in[0];   // (8M, 2) f32
    const float* incr_x = (const float*)d_in[1];   // (1023,) f32
    const float* incr_y = (const float*)d_in[2];   // (1023,) f32
    const float* u      = (const float*)d_in[3];   // (1024,1024) f32
    float* out = (float*)d_out;

    float* gx = (float*)d_ws;                          // 1024 f32
    float* gy = gx + NGRID;                            // 1024 f32
    unsigned int* UH = (unsigned int*)((char*)d_ws + 8192);  // 4 MB bf16-pair table

    size_t need = 8192 + (size_t)NGRID * NGRID * sizeof(unsigned int);

    build_grids<<<2, NGRID, 0, stream>>>(incr_x, incr_y, gx, gy);

    if (ws_size >= need) {
        int nc = NGRID * NGRID;
        build_pairs<<<(nc + 255) / 256, 256, 0, stream>>>(u, UH);

        int nq = out_size / 2;                 // 4,000,000 xy float4s
        interp_kernel6<<<1280, 512, 0, stream>>>(
            (const f32x4*)x_eval, UH, gx, gy, (f32x2*)out, nq);
    } else {
        int nf = out_size / 4;
        int blocks = (nf + 511) / 512;
        interp_kernel4<<<blocks, 512, 0, stream>>>(
            (const f32x4*)x_eval, u, gx, gy, (f32x4*)out, nf);
    }
}